// Round 1
// baseline (975.501 us; speedup 1.0000x reference)
//
#include <hip/hip_runtime.h>
#include <hip/hip_bf16.h>

#define NN 16384
#define EE 524288

constexpr int D0 = 256, D1 = 128, D2 = 64;

// ---------------- degree / CSR build ----------------

__global__ __launch_bounds__(256) void count_deg_kernel(
    const int* __restrict__ src, const int* __restrict__ dst,
    int* __restrict__ deg_out, int* __restrict__ deg_in) {
  int e = blockIdx.x * 256 + threadIdx.x;
  if (e < EE) {
    atomicAdd(&deg_out[src[e]], 1);
    atomicAdd(&deg_in[dst[e]], 1);
  }
}

__global__ __launch_bounds__(256) void norm_kernel(
    const int* __restrict__ deg_out, const int* __restrict__ deg_in,
    float* __restrict__ norm_out, float* __restrict__ norm_in) {
  int i = blockIdx.x * 256 + threadIdx.x;
  if (i < NN) {
    norm_out[i] = rsqrtf(fmaxf((float)deg_out[i], 1.0f));
    norm_in[i]  = rsqrtf(fmaxf((float)deg_in[i], 1.0f));
  }
}

// single-block exclusive prefix sum over deg_in (N = 16384 = 256 threads * 64)
__global__ __launch_bounds__(256) void prefix_kernel(
    const int* __restrict__ deg_in, int* __restrict__ row_ptr,
    int* __restrict__ cursor) {
  __shared__ int part[256];
  int t = threadIdx.x;
  int base = t * 64;
  int s = 0;
  for (int j = 0; j < 64; ++j) s += deg_in[base + j];
  part[t] = s;
  __syncthreads();
  for (int off = 1; off < 256; off <<= 1) {
    int add = (t >= off) ? part[t - off] : 0;
    __syncthreads();
    part[t] += add;
    __syncthreads();
  }
  int run = (t == 0) ? 0 : part[t - 1];
  for (int j = 0; j < 64; ++j) {
    row_ptr[base + j] = run;
    cursor[base + j] = run;
    run += deg_in[base + j];
  }
  if (t == 255) row_ptr[NN] = run;
}

__global__ __launch_bounds__(256) void fill_csr_kernel(
    const int* __restrict__ src, const int* __restrict__ dst,
    int* __restrict__ cursor, int* __restrict__ csr_src) {
  int e = blockIdx.x * 256 + threadIdx.x;
  if (e < EE) {
    int pos = atomicAdd(&cursor[dst[e]], 1);
    csr_src[pos] = src[e];
  }
}

// ---------------- fused graph-conv layer ----------------
// out[v] = act( (sum_{e: dst=v} in[src_e]*norm_out[src_e]) * norm_in[v] @ W + b )
// 4 nodes per block (amortizes W reads), 256 threads.

template<int DIN, int DOUT, bool RELU>
__global__ __launch_bounds__(256) void layer_kernel(
    const float* __restrict__ in, const float* __restrict__ W,
    const float* __restrict__ bias, const float* __restrict__ norm_out,
    const float* __restrict__ norm_in, const int* __restrict__ row_ptr,
    const int* __restrict__ csr, float* __restrict__ out) {
  constexpr int NPB = 4;
  constexpr int NH = 256 / DIN;     // edge-parallel halves in gather phase
  constexpr int SPLIT = 256 / DOUT; // split-k groups in GEMM phase
  constexpr int KC = DIN / SPLIT;
  __shared__ float rows[NPB][DIN];
  __shared__ float red[NPB][256];
  int t = threadIdx.x;
  int v0 = blockIdx.x * NPB;
  int c = t % DIN;
  int hh = t / DIN;

  // phase A: aggregate neighbors
  for (int r = 0; r < NPB; ++r) {
    int v = v0 + r;
    int k0 = row_ptr[v], k1 = row_ptr[v + 1];
    float acc = 0.f;
    for (int k = k0 + hh; k < k1; k += NH) {
      int s = csr[k];
      acc += in[s * DIN + c] * norm_out[s];
    }
    if (NH == 1) {
      rows[r][c] = acc * norm_in[v];
    } else {
      red[r][t] = acc;
      __syncthreads();
      if (t < DIN) rows[r][t] = (red[r][t] + red[r][t + DIN]) * norm_in[v];
    }
  }
  __syncthreads();

  // phase B: rows @ W (+b, act)
  int j = t % DOUT;
  int h = t / DOUT;
  float p[NPB];
#pragma unroll
  for (int r = 0; r < NPB; ++r) p[r] = 0.f;
  for (int k = h * KC; k < h * KC + KC; ++k) {
    float wv = W[k * DOUT + j];
#pragma unroll
    for (int r = 0; r < NPB; ++r) p[r] += rows[r][k] * wv;
  }
#pragma unroll
  for (int r = 0; r < NPB; ++r) red[r][t] = p[r];
  __syncthreads();
  if (t < DOUT) {
#pragma unroll
    for (int r = 0; r < NPB; ++r) {
      float o = bias[t];
#pragma unroll
      for (int q = 0; q < SPLIT; ++q) o += red[r][t + q * DOUT];
      if (RELU) o = fmaxf(o, 0.f);
      out[(v0 + r) * DOUT + t] = o;
    }
  }
}

// ---------------- adjacency reconstruction ----------------
// C = sigmoid(z @ z^T), z: [N,64] f32. 128x128 tile / block, 8x8 per thread.
// LDS tiles XOR-swizzled (slot ^= row&15) so A/B ds_read_b128 are conflict-free.

__global__ __launch_bounds__(256) void adj_kernel(
    const float* __restrict__ z, float* __restrict__ C) {
  __shared__ float ZR[128 * 64];
  __shared__ float ZC[128 * 64];
  int t = threadIdx.x;
  int tx = t & 15, ty = t >> 4;
  int bx = blockIdx.x & 127;  // col tile
  int by = blockIdx.x >> 7;   // row tile
  int row0 = by * 128, col0 = bx * 128;
  const float4* zr4 = (const float4*)(z + (size_t)row0 * 64);
  const float4* zc4 = (const float4*)(z + (size_t)col0 * 64);
#pragma unroll
  for (int i = 0; i < 8; ++i) {
    int q = t + 256 * i;       // float4 index within 128x64 tile
    int r = q >> 4;
    int slot = q & 15;
    int sw = slot ^ (r & 15);
    float4 a = zr4[q];
    float4 b = zc4[q];
    *(float4*)&ZR[r * 64 + sw * 4] = a;
    *(float4*)&ZC[r * 64 + sw * 4] = b;
  }
  __syncthreads();

  float acc[8][8];
#pragma unroll
  for (int i = 0; i < 8; ++i)
#pragma unroll
    for (int j = 0; j < 8; ++j) acc[i][j] = 0.f;

  for (int k4 = 0; k4 < 16; ++k4) {
    float4 a[8], b[8];
#pragma unroll
    for (int i = 0; i < 8; ++i) {
      int r = ty + 16 * i;     // r & 15 == ty
      a[i] = *(const float4*)&ZR[r * 64 + ((k4 ^ ty) << 2)];
    }
#pragma unroll
    for (int j = 0; j < 8; ++j) {
      int r = tx + 16 * j;     // r & 15 == tx
      b[j] = *(const float4*)&ZC[r * 64 + ((k4 ^ tx) << 2)];
    }
#pragma unroll
    for (int i = 0; i < 8; ++i)
#pragma unroll
      for (int j = 0; j < 8; ++j) {
        acc[i][j] += a[i].x * b[j].x;
        acc[i][j] += a[i].y * b[j].y;
        acc[i][j] += a[i].z * b[j].z;
        acc[i][j] += a[i].w * b[j].w;
      }
  }

#pragma unroll
  for (int i = 0; i < 8; ++i) {
    int r = row0 + ty + 16 * i;
#pragma unroll
    for (int j = 0; j < 8; ++j) {
      int cidx = col0 + tx + 16 * j;
      float x = acc[i][j];
      float sg = 1.0f / (1.0f + __expf(-x));
      C[(size_t)r * NN + cidx] = sg;
    }
  }
}

// ---------------- launch ----------------

extern "C" void kernel_launch(void* const* d_in, const int* in_sizes, int n_in,
                              void* d_out, int out_size, void* d_ws, size_t ws_size,
                              hipStream_t stream) {
  const float* features = (const float*)d_in[0];
  const int* src = (const int*)d_in[1];
  const int* dst = (const int*)d_in[2];
  const float* W1 = (const float*)d_in[3];
  const float* b1 = (const float*)d_in[4];
  const float* W2 = (const float*)d_in[5];
  const float* b2 = (const float*)d_in[6];
  const float* W3 = (const float*)d_in[7];
  const float* b3 = (const float*)d_in[8];

  float* outp = (float*)d_out;
  float* adj = outp;                         // [N, N]
  float* z = outp + (size_t)NN * NN;         // [N, 64]

  float* wsf = (float*)d_ws;
  float* norm_out = wsf;                     // N
  float* norm_in = wsf + NN;                 // N
  int* deg_out = (int*)(wsf + 2 * NN);       // N
  int* deg_in = deg_out + NN;                // N
  int* row_ptr = deg_in + NN;                // N+1
  int* cursor = row_ptr + NN + 256;          // N (padded start)
  int* csr_src = cursor + NN;                // E
  float* h1 = (float*)(csr_src + EE);        // N*128
  float* h2 = h1 + NN * D1;                  // N*128

  hipMemsetAsync(deg_out, 0, 2 * NN * sizeof(int), stream);
  count_deg_kernel<<<EE / 256, 256, 0, stream>>>(src, dst, deg_out, deg_in);
  norm_kernel<<<NN / 256, 256, 0, stream>>>(deg_out, deg_in, norm_out, norm_in);
  prefix_kernel<<<1, 256, 0, stream>>>(deg_in, row_ptr, cursor);
  fill_csr_kernel<<<EE / 256, 256, 0, stream>>>(src, dst, cursor, csr_src);

  layer_kernel<D0, D1, true><<<NN / 4, 256, 0, stream>>>(
      features, W1, b1, norm_out, norm_in, row_ptr, csr_src, h1);
  layer_kernel<D1, D1, true><<<NN / 4, 256, 0, stream>>>(
      h1, W2, b2, norm_out, norm_in, row_ptr, csr_src, h2);
  layer_kernel<D1, D2, false><<<NN / 4, 256, 0, stream>>>(
      h2, W3, b3, norm_out, norm_in, row_ptr, csr_src, z);

  adj_kernel<<<(NN / 128) * (NN / 128), 256, 0, stream>>>(z, adj);
}

// Round 2
// 483.037 us; speedup vs baseline: 2.0195x; 2.0195x over previous
//
#include <hip/hip_runtime.h>
#include <hip/hip_bf16.h>

#define NN 16384
#define EE 524288

constexpr int D0 = 256, D1 = 128, D2 = 64;

typedef __attribute__((ext_vector_type(8))) short short8;
typedef __attribute__((ext_vector_type(4))) float f32x4;

// ---------------- degree / CSR build ----------------

__global__ __launch_bounds__(256) void count_deg_kernel(
    const int* __restrict__ src, const int* __restrict__ dst,
    int* __restrict__ deg_out, int* __restrict__ deg_in) {
  int e = blockIdx.x * 256 + threadIdx.x;
  if (e < EE) {
    atomicAdd(&deg_out[src[e]], 1);
    atomicAdd(&deg_in[dst[e]], 1);
  }
}

__global__ __launch_bounds__(256) void norm_kernel(
    const int* __restrict__ deg_out, const int* __restrict__ deg_in,
    float* __restrict__ norm_out, float* __restrict__ norm_in) {
  int i = blockIdx.x * 256 + threadIdx.x;
  if (i < NN) {
    norm_out[i] = rsqrtf(fmaxf((float)deg_out[i], 1.0f));
    norm_in[i]  = rsqrtf(fmaxf((float)deg_in[i], 1.0f));
  }
}

__global__ __launch_bounds__(256) void prefix_kernel(
    const int* __restrict__ deg_in, int* __restrict__ row_ptr,
    int* __restrict__ cursor) {
  __shared__ int part[256];
  int t = threadIdx.x;
  int base = t * 64;
  int s = 0;
  for (int j = 0; j < 64; ++j) s += deg_in[base + j];
  part[t] = s;
  __syncthreads();
  for (int off = 1; off < 256; off <<= 1) {
    int add = (t >= off) ? part[t - off] : 0;
    __syncthreads();
    part[t] += add;
    __syncthreads();
  }
  int run = (t == 0) ? 0 : part[t - 1];
  for (int j = 0; j < 64; ++j) {
    row_ptr[base + j] = run;
    cursor[base + j] = run;
    run += deg_in[base + j];
  }
  if (t == 255) row_ptr[NN] = run;
}

__global__ __launch_bounds__(256) void fill_csr_kernel(
    const int* __restrict__ src, const int* __restrict__ dst,
    int* __restrict__ cursor, int* __restrict__ csr_src) {
  int e = blockIdx.x * 256 + threadIdx.x;
  if (e < EE) {
    int pos = atomicAdd(&cursor[dst[e]], 1);
    csr_src[pos] = src[e];
  }
}

// ---------------- dense GEMM: t = (h o norm_out) @ W ----------------
// 32 rows/block, A staged in LDS (coalesced + norm fused), W via L2.

template<int DIN, int DOUT>
__global__ __launch_bounds__(256) void gemm_kernel(
    const float* __restrict__ h, const float* __restrict__ W,
    const float* __restrict__ norm_out, float* __restrict__ t) {
  constexpr int W4 = DOUT / 4;   // 32 or 16
  constexpr int RG = 256 / W4;   // 8 or 16 row-groups
  constexpr int RPT = 32 / RG;   // rows per thread: 4 or 2
  __shared__ float A[32][DIN];
  int tid = threadIdx.x;
  int r0 = blockIdx.x * 32;
  constexpr int NF4 = 32 * DIN / 4;
  for (int q = tid; q < NF4; q += 256) {
    int r = q / (DIN / 4);
    int c = q % (DIN / 4);
    float4 x = *(const float4*)&h[(size_t)(r0 + r) * DIN + c * 4];
    float no = norm_out[r0 + r];
    x.x *= no; x.y *= no; x.z *= no; x.w *= no;
    *(float4*)&A[r][c * 4] = x;
  }
  __syncthreads();
  int c4 = tid % W4;
  int rg = tid / W4;
  float4 acc[RPT];
#pragma unroll
  for (int j = 0; j < RPT; ++j) acc[j] = make_float4(0.f, 0.f, 0.f, 0.f);
  const float* Wp = W + c4 * 4;
#pragma unroll 2
  for (int k = 0; k < DIN; ++k) {
    float4 w = *(const float4*)&Wp[(size_t)k * DOUT];
#pragma unroll
    for (int j = 0; j < RPT; ++j) {
      float a = A[rg + j * RG][k];
      acc[j].x += a * w.x; acc[j].y += a * w.y;
      acc[j].z += a * w.z; acc[j].w += a * w.w;
    }
  }
#pragma unroll
  for (int j = 0; j < RPT; ++j)
    *(float4*)&t[(size_t)(r0 + rg + j * RG) * DOUT + c4 * 4] = acc[j];
}

// ---------------- gather: out[v] = act(norm_in[v]*sum t[src] + b) --------
// One node/block; S edge-slots x W4 float4-channels; coalesced 512B loads.

template<int DOUT, bool RELU, bool WRITE_BF16>
__global__ __launch_bounds__(256) void gather_kernel(
    const float* __restrict__ t, const float* __restrict__ bias,
    const float* __restrict__ norm_in, const int* __restrict__ row_ptr,
    const int* __restrict__ csr, float* __restrict__ out,
    ushort* __restrict__ zb) {
  constexpr int W4 = DOUT / 4;   // 32 or 16
  constexpr int S = 256 / W4;    // 8 or 16 parallel edges
  __shared__ float4 red[256];
  int tid = threadIdx.x;
  int c4 = tid % W4, slot = tid / W4;
  int v = blockIdx.x;
  int k0 = row_ptr[v], k1 = row_ptr[v + 1];
  float4 acc = make_float4(0.f, 0.f, 0.f, 0.f);
  for (int k = k0 + slot; k < k1; k += S) {
    int s = csr[k];
    float4 m = *(const float4*)&t[(size_t)s * DOUT + c4 * 4];
    acc.x += m.x; acc.y += m.y; acc.z += m.z; acc.w += m.w;
  }
  red[tid] = acc;
  __syncthreads();
  if (tid < W4) {
    float4 a = red[tid];
#pragma unroll
    for (int s = 1; s < S; ++s) {
      float4 b = red[s * W4 + tid];
      a.x += b.x; a.y += b.y; a.z += b.z; a.w += b.w;
    }
    float ni = norm_in[v];
    float4 b4 = *(const float4*)&bias[tid * 4];
    a.x = a.x * ni + b4.x; a.y = a.y * ni + b4.y;
    a.z = a.z * ni + b4.z; a.w = a.w * ni + b4.w;
    if (RELU) {
      a.x = fmaxf(a.x, 0.f); a.y = fmaxf(a.y, 0.f);
      a.z = fmaxf(a.z, 0.f); a.w = fmaxf(a.w, 0.f);
    }
    *(float4*)&out[(size_t)v * DOUT + tid * 4] = a;
    if (WRITE_BF16) {
      float vals[4] = {a.x, a.y, a.z, a.w};
#pragma unroll
      for (int i = 0; i < 4; ++i) {
        __hip_bfloat16 hb = __float2bfloat16(vals[i]);
        zb[(size_t)v * DOUT + tid * 4 + i] = *reinterpret_cast<ushort*>(&hb);
      }
    }
  }
}

// ---------------- adjacency: C = sigmoid(zb @ zb^T) via bf16 MFMA --------
// 128x128 tile/block, 4 waves (2x2), each wave 64x64 via 16x16x32 MFMA.
// LDS tiles XOR-swizzled in 16B units: unit u of row r stored at u^(r&7).

__global__ __launch_bounds__(256) void adj_mfma_kernel(
    const ushort* __restrict__ zb, float* __restrict__ C) {
  __shared__ ushort ZR[128 * 64];
  __shared__ ushort ZC[128 * 64];
  int t = threadIdx.x;
  int bx = blockIdx.x & 127, by = blockIdx.x >> 7;
  int row0 = by * 128, col0 = bx * 128;
  {
    int r = t >> 1;
    int ub = (t & 1) * 4;
    const float4* zr = (const float4*)(zb + (size_t)(row0 + r) * 64);
    const float4* zc = (const float4*)(zb + (size_t)(col0 + r) * 64);
    float4* LR = (float4*)ZR;
    float4* LC = (float4*)ZC;
#pragma unroll
    for (int u = 0; u < 4; ++u) {
      int sw = (ub + u) ^ (r & 7);
      LR[r * 8 + sw] = zr[ub + u];
      LC[r * 8 + sw] = zc[ub + u];
    }
  }
  __syncthreads();
  int l = t & 63, w = t >> 6;
  int wy = w >> 1, wx = w & 1;
  int lr = l & 15, lg = l >> 4;  // lane-row (0..15), k-group (0..3)
  f32x4 acc[4][4];
#pragma unroll
  for (int i = 0; i < 4; ++i)
#pragma unroll
    for (int j = 0; j < 4; ++j) acc[i][j] = (f32x4){0.f, 0.f, 0.f, 0.f};

#pragma unroll
  for (int ks = 0; ks < 2; ++ks) {
    short8 af[4], bf_[4];
    int u = ks * 4 + lg;
#pragma unroll
    for (int i = 0; i < 4; ++i) {
      int ar = wy * 64 + i * 16 + lr;  // A: lane holds z[ar][k..k+7]
      af[i] = *(const short8*)&ZR[ar * 64 + ((u ^ (ar & 7)) << 3)];
      int ac = wx * 64 + i * 16 + lr;  // B: lane holds z[ac][k..k+7]
      bf_[i] = *(const short8*)&ZC[ac * 64 + ((u ^ (ac & 7)) << 3)];
    }
#pragma unroll
    for (int i = 0; i < 4; ++i)
#pragma unroll
      for (int j = 0; j < 4; ++j)
        acc[i][j] = __builtin_amdgcn_mfma_f32_16x16x32_bf16(
            af[i], bf_[j], acc[i][j], 0, 0, 0);
  }

  // C/D layout (m89-verified): col = lane&15, row = (lane>>4)*4 + reg
#pragma unroll
  for (int i = 0; i < 4; ++i) {
#pragma unroll
    for (int q = 0; q < 4; ++q) {
      int row = row0 + wy * 64 + i * 16 + lg * 4 + q;
#pragma unroll
      for (int j = 0; j < 4; ++j) {
        int col = col0 + wx * 64 + j * 16 + lr;
        float x = acc[i][j][q];
        C[(size_t)row * NN + col] = 1.0f / (1.0f + __expf(-x));
      }
    }
  }
}

// ---------------- launch ----------------

extern "C" void kernel_launch(void* const* d_in, const int* in_sizes, int n_in,
                              void* d_out, int out_size, void* d_ws, size_t ws_size,
                              hipStream_t stream) {
  const float* features = (const float*)d_in[0];
  const int* src = (const int*)d_in[1];
  const int* dst = (const int*)d_in[2];
  const float* W1 = (const float*)d_in[3];
  const float* b1 = (const float*)d_in[4];
  const float* W2 = (const float*)d_in[5];
  const float* b2 = (const float*)d_in[6];
  const float* W3 = (const float*)d_in[7];
  const float* b3 = (const float*)d_in[8];

  float* outp = (float*)d_out;
  float* adj = outp;                      // [N, N]
  float* z = outp + (size_t)NN * NN;      // [N, 64]

  // intermediate buffers live in the adj region (dead before adj kernel)
  float* tA = adj;                        // N*128
  float* tB = adj + (size_t)NN * 128;     // N*128
  float* tC = adj + (size_t)2 * NN * 128; // N*128

  float* wsf = (float*)d_ws;
  float* norm_out = wsf;                  // N
  float* norm_in = wsf + NN;              // N
  int* deg_out = (int*)(wsf + 2 * NN);    // N
  int* deg_in = deg_out + NN;             // N
  int* row_ptr = deg_in + NN;             // N+1 (+pad)
  int* cursor = row_ptr + NN + 256;       // N
  int* csr_src = cursor + NN;             // E
  ushort* zb = (ushort*)(csr_src + EE);   // N*64 bf16

  hipMemsetAsync(deg_out, 0, 2 * NN * sizeof(int), stream);
  count_deg_kernel<<<EE / 256, 256, 0, stream>>>(src, dst, deg_out, deg_in);
  norm_kernel<<<NN / 256, 256, 0, stream>>>(deg_out, deg_in, norm_out, norm_in);
  prefix_kernel<<<1, 256, 0, stream>>>(deg_in, row_ptr, cursor);
  fill_csr_kernel<<<EE / 256, 256, 0, stream>>>(src, dst, cursor, csr_src);

  // layer 1: t = (features o n) W1 ; h1 = relu(agg(t) o n_in + b1)
  gemm_kernel<D0, D1><<<NN / 32, 256, 0, stream>>>(features, W1, norm_out, tA);
  gather_kernel<D1, true, false><<<NN, 256, 0, stream>>>(
      tA, b1, norm_in, row_ptr, csr_src, tB, nullptr);
  // layer 2
  gemm_kernel<D1, D1><<<NN / 32, 256, 0, stream>>>(tB, W2, norm_out, tC);
  gather_kernel<D1, true, false><<<NN, 256, 0, stream>>>(
      tC, b2, norm_in, row_ptr, csr_src, tA, nullptr);
  // layer 3 (no relu) -> z fp32 + zb bf16
  gemm_kernel<D1, D2><<<NN / 32, 256, 0, stream>>>(tA, W3, norm_out, tB);
  gather_kernel<D2, false, true><<<NN, 256, 0, stream>>>(
      tB, b3, norm_in, row_ptr, csr_src, z, zb);

  adj_mfma_kernel<<<(NN / 128) * (NN / 128), 256, 0, stream>>>(zb, adj);
}

// Round 4
// 478.080 us; speedup vs baseline: 2.0405x; 1.0104x over previous
//
#include <hip/hip_runtime.h>
#include <hip/hip_bf16.h>

#define NN 16384
#define EE 524288

constexpr int D0 = 256, D1 = 128, D2 = 64;

typedef __attribute__((ext_vector_type(8))) short short8;
typedef __attribute__((ext_vector_type(4))) float f32x4;

__device__ __forceinline__ float b2f(ushort u) {
  union { unsigned int i; float f; } x;
  x.i = ((unsigned int)u) << 16;
  return x.f;
}

// ---------------- degree / CSR build ----------------

__global__ __launch_bounds__(256) void count_deg_kernel(
    const int* __restrict__ src, const int* __restrict__ dst,
    int* __restrict__ deg_out, int* __restrict__ deg_in) {
  int e = blockIdx.x * 256 + threadIdx.x;
  if (e < EE) {
    atomicAdd(&deg_out[src[e]], 1);
    atomicAdd(&deg_in[dst[e]], 1);
  }
}

__global__ __launch_bounds__(256) void norm_kernel(
    const int* __restrict__ deg_out, const int* __restrict__ deg_in,
    float* __restrict__ norm_out, float* __restrict__ norm_in) {
  int i = blockIdx.x * 256 + threadIdx.x;
  if (i < NN) {
    norm_out[i] = rsqrtf(fmaxf((float)deg_out[i], 1.0f));
    norm_in[i]  = rsqrtf(fmaxf((float)deg_in[i], 1.0f));
  }
}

__global__ __launch_bounds__(256) void prefix_kernel(
    const int* __restrict__ deg_in, int* __restrict__ row_ptr,
    int* __restrict__ cursor) {
  __shared__ int part[256];
  int t = threadIdx.x;
  int base = t * 64;
  int s = 0;
  for (int j = 0; j < 64; ++j) s += deg_in[base + j];
  part[t] = s;
  __syncthreads();
  for (int off = 1; off < 256; off <<= 1) {
    int add = (t >= off) ? part[t - off] : 0;
    __syncthreads();
    part[t] += add;
    __syncthreads();
  }
  int run = (t == 0) ? 0 : part[t - 1];
  for (int j = 0; j < 64; ++j) {
    row_ptr[base + j] = run;
    cursor[base + j] = run;
    run += deg_in[base + j];
  }
  if (t == 255) row_ptr[NN] = run;
}

__global__ __launch_bounds__(256) void fill_csr_kernel(
    const int* __restrict__ src, const int* __restrict__ dst,
    int* __restrict__ cursor, int* __restrict__ csr_src) {
  int e = blockIdx.x * 256 + threadIdx.x;
  if (e < EE) {
    int pos = atomicAdd(&cursor[dst[e]], 1);
    csr_src[pos] = src[e];
  }
}

// ---------------- dense GEMM: t = (h o norm_out) @ W ----------------
// 32 rows/block. OBF16: write t as bf16 (halves gather traffic).

template<int DIN, int DOUT, bool OBF16>
__global__ __launch_bounds__(256) void gemm_kernel(
    const float* __restrict__ h, const float* __restrict__ W,
    const float* __restrict__ norm_out, float* __restrict__ tf,
    ushort* __restrict__ tb) {
  constexpr int W4 = DOUT / 4;   // 32 or 16
  constexpr int RG = 256 / W4;   // 8 or 16 row-groups
  constexpr int RPT = 32 / RG;   // rows per thread: 4 or 2
  __shared__ float A[32][DIN];
  int tid = threadIdx.x;
  int r0 = blockIdx.x * 32;
  constexpr int NF4 = 32 * DIN / 4;
  for (int q = tid; q < NF4; q += 256) {
    int r = q / (DIN / 4);
    int c = q % (DIN / 4);
    float4 x = *(const float4*)&h[(size_t)(r0 + r) * DIN + c * 4];
    float no = norm_out[r0 + r];
    x.x *= no; x.y *= no; x.z *= no; x.w *= no;
    *(float4*)&A[r][c * 4] = x;
  }
  __syncthreads();
  int c4 = tid % W4;
  int rg = tid / W4;
  float4 acc[RPT];
#pragma unroll
  for (int j = 0; j < RPT; ++j) acc[j] = make_float4(0.f, 0.f, 0.f, 0.f);
  const float* Wp = W + c4 * 4;
#pragma unroll 2
  for (int k = 0; k < DIN; ++k) {
    float4 w = *(const float4*)&Wp[(size_t)k * DOUT];
#pragma unroll
    for (int j = 0; j < RPT; ++j) {
      float a = A[rg + j * RG][k];
      acc[j].x += a * w.x; acc[j].y += a * w.y;
      acc[j].z += a * w.z; acc[j].w += a * w.w;
    }
  }
#pragma unroll
  for (int j = 0; j < RPT; ++j) {
    size_t row = (size_t)(r0 + rg + j * RG);
    if (OBF16) {
      ushort4 o;
      __hip_bfloat16 h0 = __float2bfloat16(acc[j].x);
      __hip_bfloat16 h1 = __float2bfloat16(acc[j].y);
      __hip_bfloat16 h2 = __float2bfloat16(acc[j].z);
      __hip_bfloat16 h3 = __float2bfloat16(acc[j].w);
      o.x = *reinterpret_cast<ushort*>(&h0);
      o.y = *reinterpret_cast<ushort*>(&h1);
      o.z = *reinterpret_cast<ushort*>(&h2);
      o.w = *reinterpret_cast<ushort*>(&h3);
      *(ushort4*)&tb[row * DOUT + c4 * 4] = o;
    } else {
      *(float4*)&tf[row * DOUT + c4 * 4] = acc[j];
    }
  }
}

// ---------------- gather (bf16 t): out fp32 ----------------
// One node/block. 16 edge-slots x 16 8-channel groups; 16B coalesced loads.

template<int DOUT, bool RELU>
__global__ __launch_bounds__(256) void gather_bf16_kernel(
    const ushort* __restrict__ t, const float* __restrict__ bias,
    const float* __restrict__ norm_in, const int* __restrict__ row_ptr,
    const int* __restrict__ csr, float* __restrict__ out) {
  constexpr int G8 = DOUT / 8;   // 16
  constexpr int S = 256 / G8;    // 16
  __shared__ float red[S][G8][8];
  int tid = threadIdx.x;
  int c8 = tid % G8, slot = tid / G8;
  int v = blockIdx.x;
  int k0 = row_ptr[v], k1 = row_ptr[v + 1];
  float a[8];
#pragma unroll
  for (int i = 0; i < 8; ++i) a[i] = 0.f;
  for (int k = k0 + slot; k < k1; k += S) {
    int s = csr[k];
    short8 m = *(const short8*)&t[(size_t)s * DOUT + c8 * 8];
#pragma unroll
    for (int i = 0; i < 8; ++i) a[i] += b2f((ushort)m[i]);
  }
#pragma unroll
  for (int i = 0; i < 8; ++i) red[slot][c8][i] = a[i];
  __syncthreads();
#pragma unroll
  for (int s = S / 2; s >= 1; s >>= 1) {
    if (slot < s) {
#pragma unroll
      for (int i = 0; i < 8; ++i) red[slot][c8][i] += red[slot + s][c8][i];
    }
    __syncthreads();
  }
  if (tid < G8) {
    float ni = norm_in[v];
    float o[8];
#pragma unroll
    for (int i = 0; i < 8; ++i) {
      o[i] = red[0][tid][i] * ni + bias[tid * 8 + i];
      if (RELU) o[i] = fmaxf(o[i], 0.f);
    }
    *(float4*)&out[(size_t)v * DOUT + tid * 8] = make_float4(o[0], o[1], o[2], o[3]);
    *(float4*)&out[(size_t)v * DOUT + tid * 8 + 4] = make_float4(o[4], o[5], o[6], o[7]);
  }
}

// ---------------- gather (fp32 t), layer 3: writes z fp32 + zb bf16 ------

template<int DOUT, bool RELU>
__global__ __launch_bounds__(256) void gather_f32_kernel(
    const float* __restrict__ t, const float* __restrict__ bias,
    const float* __restrict__ norm_in, const int* __restrict__ row_ptr,
    const int* __restrict__ csr, float* __restrict__ out,
    ushort* __restrict__ zb) {
  constexpr int W4 = DOUT / 4;   // 16
  constexpr int S = 256 / W4;    // 16
  __shared__ float4 red[256];
  int tid = threadIdx.x;
  int c4 = tid % W4, slot = tid / W4;
  int v = blockIdx.x;
  int k0 = row_ptr[v], k1 = row_ptr[v + 1];
  float4 acc = make_float4(0.f, 0.f, 0.f, 0.f);
  for (int k = k0 + slot; k < k1; k += S) {
    int s = csr[k];
    float4 m = *(const float4*)&t[(size_t)s * DOUT + c4 * 4];
    acc.x += m.x; acc.y += m.y; acc.z += m.z; acc.w += m.w;
  }
  red[tid] = acc;
  __syncthreads();
  if (tid < W4) {
    float4 a = red[tid];
#pragma unroll
    for (int s = 1; s < S; ++s) {
      float4 b = red[s * W4 + tid];
      a.x += b.x; a.y += b.y; a.z += b.z; a.w += b.w;
    }
    float ni = norm_in[v];
    float4 b4 = *(const float4*)&bias[tid * 4];
    a.x = a.x * ni + b4.x; a.y = a.y * ni + b4.y;
    a.z = a.z * ni + b4.z; a.w = a.w * ni + b4.w;
    if (RELU) {
      a.x = fmaxf(a.x, 0.f); a.y = fmaxf(a.y, 0.f);
      a.z = fmaxf(a.z, 0.f); a.w = fmaxf(a.w, 0.f);
    }
    *(float4*)&out[(size_t)v * DOUT + tid * 4] = a;
    float vals[4] = {a.x, a.y, a.z, a.w};
    ushort4 ob;
    __hip_bfloat16 h0 = __float2bfloat16(vals[0]);
    __hip_bfloat16 h1 = __float2bfloat16(vals[1]);
    __hip_bfloat16 h2 = __float2bfloat16(vals[2]);
    __hip_bfloat16 h3 = __float2bfloat16(vals[3]);
    ob.x = *reinterpret_cast<ushort*>(&h0);
    ob.y = *reinterpret_cast<ushort*>(&h1);
    ob.z = *reinterpret_cast<ushort*>(&h2);
    ob.w = *reinterpret_cast<ushort*>(&h3);
    *(ushort4*)&zb[(size_t)v * DOUT + tid * 4] = ob;
  }
}

// ---------------- adjacency: C = sigmoid(zb @ zb^T) via bf16 MFMA --------
// 128x128 tile/block, 4 waves (2x2). Operand-swapped MFMA (mfma(B,A)) so
// each accumulator quad = 4 consecutive C-columns -> float4 stores.
// zb lives in d_ws (NOT in adj — adj blocks race with reads otherwise).

__global__ __launch_bounds__(256) void adj_mfma_kernel(
    const ushort* __restrict__ zb, float* __restrict__ C) {
  __shared__ ushort ZR[128 * 64];
  __shared__ ushort ZC[128 * 64];
  int t = threadIdx.x;
  int bx = blockIdx.x & 127, by = blockIdx.x >> 7;
  int row0 = by * 128, col0 = bx * 128;
  {
    int r = t >> 1;
    int ub = (t & 1) * 4;
    const float4* zr = (const float4*)(zb + (size_t)(row0 + r) * 64);
    const float4* zc = (const float4*)(zb + (size_t)(col0 + r) * 64);
    float4* LR = (float4*)ZR;
    float4* LC = (float4*)ZC;
#pragma unroll
    for (int u = 0; u < 4; ++u) {
      int sw = (ub + u) ^ (r & 7);
      LR[r * 8 + sw] = zr[ub + u];
      LC[r * 8 + sw] = zc[ub + u];
    }
  }
  __syncthreads();
  int l = t & 63, w = t >> 6;
  int wy = w >> 1, wx = w & 1;
  int lr = l & 15, lg = l >> 4;
  f32x4 acc[4][4];
#pragma unroll
  for (int i = 0; i < 4; ++i)
#pragma unroll
    for (int j = 0; j < 4; ++j) acc[i][j] = (f32x4){0.f, 0.f, 0.f, 0.f};

#pragma unroll
  for (int ks = 0; ks < 2; ++ks) {
    short8 af[4], bf_[4];
    int u = ks * 4 + lg;
#pragma unroll
    for (int i = 0; i < 4; ++i) {
      int ar = wy * 64 + i * 16 + lr;
      af[i] = *(const short8*)&ZR[ar * 64 + ((u ^ (ar & 7)) << 3)];
      int ac = wx * 64 + i * 16 + lr;
      bf_[i] = *(const short8*)&ZC[ac * 64 + ((u ^ (ac & 7)) << 3)];
    }
    // swapped operands: n'=lane&15 -> C-row, m'=(lane>>4)*4+reg -> C-col
#pragma unroll
    for (int i = 0; i < 4; ++i)
#pragma unroll
      for (int j = 0; j < 4; ++j)
        acc[i][j] = __builtin_amdgcn_mfma_f32_16x16x32_bf16(
            bf_[j], af[i], acc[i][j], 0, 0, 0);
  }

#pragma unroll
  for (int i = 0; i < 4; ++i) {
    int crow = row0 + wy * 64 + i * 16 + lr;
    float* Crow = C + (size_t)crow * NN;
#pragma unroll
    for (int j = 0; j < 4; ++j) {
      int ccol = col0 + wx * 64 + j * 16 + lg * 4;
      float4 o;
      o.x = __builtin_amdgcn_rcpf(1.0f + __expf(-acc[i][j][0]));
      o.y = __builtin_amdgcn_rcpf(1.0f + __expf(-acc[i][j][1]));
      o.z = __builtin_amdgcn_rcpf(1.0f + __expf(-acc[i][j][2]));
      o.w = __builtin_amdgcn_rcpf(1.0f + __expf(-acc[i][j][3]));
      *(float4*)&Crow[ccol] = o;
    }
  }
}

// ---------------- launch ----------------

extern "C" void kernel_launch(void* const* d_in, const int* in_sizes, int n_in,
                              void* d_out, int out_size, void* d_ws, size_t ws_size,
                              hipStream_t stream) {
  const float* features = (const float*)d_in[0];
  const int* src = (const int*)d_in[1];
  const int* dst = (const int*)d_in[2];
  const float* W1 = (const float*)d_in[3];
  const float* b1 = (const float*)d_in[4];
  const float* W2 = (const float*)d_in[5];
  const float* b2 = (const float*)d_in[6];
  const float* W3 = (const float*)d_in[7];
  const float* b3 = (const float*)d_in[8];

  float* outp = (float*)d_out;
  float* adj = outp;                      // [N, N]
  float* z = outp + (size_t)NN * NN;      // [N, 64]

  // scratch inside adj — all DEAD before adj_mfma launches (no aliasing with
  // anything adj_mfma reads):
  ushort* tb = (ushort*)adj;              // N*128 bf16 (4 MB), t1/t2
  float* hbuf = adj + (size_t)NN * 64;    // N*128 fp32 (h1, then h2)
  float* t3 = adj + (size_t)NN * 192;     // N*64 fp32

  float* wsf = (float*)d_ws;
  float* norm_out = wsf;                  // N
  float* norm_in = wsf + NN;              // N
  int* deg_out = (int*)(wsf + 2 * NN);    // N
  int* deg_in = deg_out + NN;             // N
  int* row_ptr = deg_in + NN;             // N+1 (+pad)
  int* cursor = row_ptr + NN + 256;       // N
  int* csr_src = cursor + NN;             // E
  ushort* zb = (ushort*)(csr_src + EE);   // N*64 bf16 — in d_ws, NOT adj!

  hipMemsetAsync(deg_out, 0, 2 * NN * sizeof(int), stream);
  count_deg_kernel<<<EE / 256, 256, 0, stream>>>(src, dst, deg_out, deg_in);
  norm_kernel<<<NN / 256, 256, 0, stream>>>(deg_out, deg_in, norm_out, norm_in);
  prefix_kernel<<<1, 256, 0, stream>>>(deg_in, row_ptr, cursor);
  fill_csr_kernel<<<EE / 256, 256, 0, stream>>>(src, dst, cursor, csr_src);

  // layer 1: t1(bf16) = (x o n)W1 ; h1 = relu(agg(t1) o n_in + b1)
  gemm_kernel<D0, D1, true><<<NN / 32, 256, 0, stream>>>(
      features, W1, norm_out, nullptr, tb);
  gather_bf16_kernel<D1, true><<<NN, 256, 0, stream>>>(
      tb, b1, norm_in, row_ptr, csr_src, hbuf);
  // layer 2
  gemm_kernel<D1, D1, true><<<NN / 32, 256, 0, stream>>>(
      hbuf, W2, norm_out, nullptr, tb);
  gather_bf16_kernel<D1, true><<<NN, 256, 0, stream>>>(
      tb, b2, norm_in, row_ptr, csr_src, hbuf);
  // layer 3 (no relu): t3 fp32, gather writes z fp32 + zb bf16 (zb in d_ws)
  gemm_kernel<D1, D2, false><<<NN / 32, 256, 0, stream>>>(
      hbuf, W3, norm_out, t3, nullptr);
  gather_f32_kernel<D2, false><<<NN, 256, 0, stream>>>(
      t3, b3, norm_in, row_ptr, csr_src, z, zb);

  adj_mfma_kernel<<<(NN / 128) * (NN / 128), 256, 0, stream>>>(zb, adj);
}